// Round 1
// baseline (1840.682 us; speedup 1.0000x reference)
//
#include <hip/hip_runtime.h>

// Problem constants (from reference): B=8, T=2048, C=1024
constexpr int Cdim  = 1024;
constexpr int Bn    = 8;
constexpr int Tn    = 2048;
constexpr int Mrows = Bn * Tn;   // 16384 rows for all GEMMs

// Tiled fp32 NT-GEMM: out[m,n] = dot(X[m,:], W[n,:]); X is [M,C], W is [N,C],
// both row-major with K (=C) contiguous. BM=BN=64, BK=16, 256 threads,
// 4x4 accumulators per thread. DUAL computes two GEMMs sharing the A tile
// (value_w -> O0 plain, recep_w -> O1 with sigmoid).
constexpr int BM = 64, BN = 64, BK = 16;

template <bool DUAL>
__global__ __launch_bounds__(256)
void gemm_nt_kernel(const float* __restrict__ X,
                    const float* __restrict__ W0,
                    const float* __restrict__ W1,
                    float* __restrict__ O0,
                    float* __restrict__ O1)
{
    // +4 pad keeps 16B alignment for float4 LDS reads (row = 68 floats = 272B = 17*16)
    __shared__ float As [BK][BM + 4];
    __shared__ float Bs0[BK][BN + 4];
    __shared__ float Bs1[BK][BN + 4];   // unused when !DUAL (13KB total LDS, fine)

    const int tid = threadIdx.x;
    const int m0  = blockIdx.y * BM;
    const int n0  = blockIdx.x * BN;

    // staging: 256 threads load a 64x16 tile as one float4 each, store transposed
    const int lrow = tid >> 2;   // 0..63
    const int lkq  = tid & 3;    // 0..3 -> k sub-quad

    // compute mapping: 16x16 thread grid, each thread owns 4 rows x 4 cols
    const int tx = tid & 15;
    const int ty = tid >> 4;

    float acc0[4][4] = {{0.f}};
    float acc1[4][4] = {{0.f}};

    for (int kt = 0; kt < Cdim; kt += BK) {
        const float4 a = *(const float4*)&X[(size_t)(m0 + lrow) * Cdim + kt + lkq * 4];
        As[lkq * 4 + 0][lrow] = a.x;
        As[lkq * 4 + 1][lrow] = a.y;
        As[lkq * 4 + 2][lrow] = a.z;
        As[lkq * 4 + 3][lrow] = a.w;

        const float4 b0 = *(const float4*)&W0[(size_t)(n0 + lrow) * Cdim + kt + lkq * 4];
        Bs0[lkq * 4 + 0][lrow] = b0.x;
        Bs0[lkq * 4 + 1][lrow] = b0.y;
        Bs0[lkq * 4 + 2][lrow] = b0.z;
        Bs0[lkq * 4 + 3][lrow] = b0.w;

        if constexpr (DUAL) {
            const float4 b1 = *(const float4*)&W1[(size_t)(n0 + lrow) * Cdim + kt + lkq * 4];
            Bs1[lkq * 4 + 0][lrow] = b1.x;
            Bs1[lkq * 4 + 1][lrow] = b1.y;
            Bs1[lkq * 4 + 2][lrow] = b1.z;
            Bs1[lkq * 4 + 3][lrow] = b1.w;
        }
        __syncthreads();

        #pragma unroll
        for (int k = 0; k < BK; ++k) {
            const float4 av = *(const float4*)&As[k][ty * 4];
            const float aR[4] = {av.x, av.y, av.z, av.w};

            const float4 bv0 = *(const float4*)&Bs0[k][tx * 4];
            const float b0R[4] = {bv0.x, bv0.y, bv0.z, bv0.w};
            #pragma unroll
            for (int i = 0; i < 4; ++i)
                #pragma unroll
                for (int j = 0; j < 4; ++j)
                    acc0[i][j] += aR[i] * b0R[j];

            if constexpr (DUAL) {
                const float4 bv1 = *(const float4*)&Bs1[k][tx * 4];
                const float b1R[4] = {bv1.x, bv1.y, bv1.z, bv1.w};
                #pragma unroll
                for (int i = 0; i < 4; ++i)
                    #pragma unroll
                    for (int j = 0; j < 4; ++j)
                        acc1[i][j] += aR[i] * b1R[j];
            }
        }
        __syncthreads();
    }

    #pragma unroll
    for (int i = 0; i < 4; ++i) {
        const size_t orow = (size_t)(m0 + ty * 4 + i) * Cdim + n0 + tx * 4;
        float4 o0;
        o0.x = acc0[i][0]; o0.y = acc0[i][1]; o0.z = acc0[i][2]; o0.w = acc0[i][3];
        *(float4*)&O0[orow] = o0;
        if constexpr (DUAL) {
            float4 o1;
            o1.x = 1.f / (1.f + __expf(-acc1[i][0]));
            o1.y = 1.f / (1.f + __expf(-acc1[i][1]));
            o1.z = 1.f / (1.f + __expf(-acc1[i][2]));
            o1.w = 1.f / (1.f + __expf(-acc1[i][3]));
            *(float4*)&O1[orow] = o1;
        }
    }
}

// WKV scan: one thread per (b,c) chain; sequential over T. Reads V from VRW,
// writes r*wkv back into the same buffer (read-before-write within the
// owning thread, so in-place is safe; VRW deliberately NOT __restrict__).
__global__ __launch_bounds__(256)
void wkv_kernel(float* VRW,
                const float* __restrict__ Rg,
                const float* __restrict__ td,
                const float* __restrict__ tf)
{
    const int tid = blockIdx.x * blockDim.x + threadIdx.x;  // 0..8191
    const int b = tid >> 10;
    const int c = tid & (Cdim - 1);

    float aa = 0.f, bb = 0.f, pp = -10000.0f;
    const float tdc = td[c];
    const float tfc = tf[c];

    size_t idx = (size_t)b * Tn * Cdim + c;
    for (int t = 0; t < Tn; ++t, idx += Cdim) {
        const float vt = VRW[idx];
        const float rt = Rg[idx];

        const float ww = tfc + pp;
        const float p  = fmaxf(pp, ww);
        const float e1 = __expf(pp - p);
        const float e2 = __expf(ww - p);
        const float wkv = (e1 * aa + e2 * vt) / (e1 * bb + e2 + 1e-6f);
        VRW[idx] = wkv * rt;

        const float ww2 = tdc + pp;
        const float p2  = fmaxf(pp, ww2);
        const float e1b = __expf(pp - p2);
        const float e2b = __expf(ww2 - p2);
        aa = e1b * aa + e2b * vt;
        bb = e1b * bb + e2b;
        pp = p2;
    }
}

extern "C" void kernel_launch(void* const* d_in, const int* in_sizes, int n_in,
                              void* d_out, int out_size, void* d_ws, size_t ws_size,
                              hipStream_t stream)
{
    // setup_inputs order: x, time_decay, time_first, key_w, value_w, recep_w, out_w
    const float* x       = (const float*)d_in[0];
    const float* td      = (const float*)d_in[1];
    const float* tf      = (const float*)d_in[2];
    // d_in[3] = key_w -- dead in the reference (kt unpacked, never used). Skipped.
    const float* value_w = (const float*)d_in[4];
    const float* recep_w = (const float*)d_in[5];
    const float* out_w   = (const float*)d_in[6];
    float* out = (float*)d_out;

    float* V = (float*)d_ws;                    // [M, C] fp32 = 64 MB
    float* R = V + (size_t)Mrows * Cdim;        // [M, C] fp32 = 64 MB

    dim3 grid(Cdim / BN, Mrows / BM);           // (16, 256)

    // 1) V = X @ value_w^T ; R = sigmoid(X @ recep_w^T)   (shared A tile)
    gemm_nt_kernel<true><<<grid, 256, 0, stream>>>(x, value_w, recep_w, V, R);

    // 2) in-place: V <- r * wkv(V)
    wkv_kernel<<<(Bn * Cdim) / 256, 256, 0, stream>>>(V, R, td, tf);

    // 3) out = (r*wkv) @ out_w^T
    gemm_nt_kernel<false><<<grid, 256, 0, stream>>>(V, out_w, nullptr, out, nullptr);
}

// Round 2
// 350.768 us; speedup vs baseline: 5.2476x; 5.2476x over previous
//
#include <hip/hip_runtime.h>

using u16 = unsigned short;
using u32 = unsigned int;

// Problem constants: B=8, T=2048, C=1024
constexpr int Cdim  = 1024;
constexpr int Bn    = 8;
constexpr int Tn    = 2048;
constexpr int Mrows = Bn * Tn;          // 16384 rows in all GEMMs
constexpr int NCH   = 16;               // wkv chunks per chain
constexpr int CLEN  = Tn / NCH;         // 128 steps per chunk

// ---------- bf16 helpers (bit-level, RNE) ----------
__device__ inline u16 f2bf(float x) {
    u32 u = __float_as_uint(x);
    u += 0x7fffu + ((u >> 16) & 1u);
    return (u16)(u >> 16);
}
__device__ inline float bf2f(u16 x) {
    return __uint_as_float(((u32)x) << 16);
}

// ---------- fp32 -> bf16 cast kernel (vectorized) ----------
__global__ __launch_bounds__(256)
void cast_f32_bf16(const float* __restrict__ in, u16* __restrict__ out, int n4) {
    int i = blockIdx.x * 256 + threadIdx.x;
    if (i < n4) {
        float4 v = ((const float4*)in)[i];
        ushort4 o;
        o.x = f2bf(v.x); o.y = f2bf(v.y); o.z = f2bf(v.z); o.w = f2bf(v.w);
        ((ushort4*)out)[i] = o;
    }
}

// ---------- MFMA bf16 NT-GEMM ----------
// out[m,n] = sum_k A[m,k]*W[n,k];  A:[16384,1024] bf16, W:[1024,1024] bf16.
// 128x128 tile, BK=32, 256 threads = 4 waves in 2x2; each wave 4x4 mfma
// 16x16x32 tiles. global_load_lds width=16 staging (m97 structure).
typedef __bf16 bf16x8 __attribute__((ext_vector_type(8)));
typedef float  f32x4  __attribute__((ext_vector_type(4)));

__device__ inline void load_lds16(const void* g, void* l) {
    __builtin_amdgcn_global_load_lds(
        (const __attribute__((address_space(1))) void*)g,
        (__attribute__((address_space(3))) void*)l, 16, 0, 0);
}

template <bool SIGMOID, bool OUT_BF16>
__global__ __launch_bounds__(256)
void gemm_mfma(const u16* __restrict__ A, const u16* __restrict__ W, void* __restrict__ O)
{
    __shared__ alignas(16) u16 As[128 * 32];
    __shared__ alignas(16) u16 Bs[128 * 32];

    const int tid  = threadIdx.x;
    const int wave = tid >> 6;
    const int lane = tid & 63;
    const int m0 = blockIdx.y * 128;
    const int n0 = blockIdx.x * 128;

    const int wr = wave >> 1;           // 0..1 : row-half of tile
    const int wc = wave & 1;            // 0..1 : col-half of tile

    // staging lane mapping: 1 KB per instruction, 16 rows x 64B
    const int srow = (lane >> 2);       // 0..15 row within 16-row slab
    const int scol = (lane & 3) * 8;    // element offset in K (8 bf16 = 16B)

    f32x4 acc[4][4] = {};

    for (int kt = 0; kt < Cdim; kt += 32) {
        #pragma unroll
        for (int p = 0; p < 2; ++p) {
            const int row = wave * 32 + p * 16 + srow;
            const int lo  = wave * 2048 + p * 1024;     // LDS byte offset (wave-uniform)
            load_lds16(A + (size_t)(m0 + row) * Cdim + kt + scol, (char*)As + lo);
            load_lds16(W + (size_t)(n0 + row) * Cdim + kt + scol, (char*)Bs + lo);
        }
        __syncthreads();

        bf16x8 af[4], bfr[4];
        #pragma unroll
        for (int i = 0; i < 4; ++i) {
            af[i]  = *(const bf16x8*)&As[(wr * 64 + i * 16 + (lane & 15)) * 32 + (lane >> 4) * 8];
            bfr[i] = *(const bf16x8*)&Bs[(wc * 64 + i * 16 + (lane & 15)) * 32 + (lane >> 4) * 8];
        }
        #pragma unroll
        for (int i = 0; i < 4; ++i)
            #pragma unroll
            for (int j = 0; j < 4; ++j)
                acc[i][j] = __builtin_amdgcn_mfma_f32_16x16x32_bf16(af[i], bfr[j], acc[i][j], 0, 0, 0);
        __syncthreads();
    }

    // epilogue: C/D layout col=lane&15, row=(lane>>4)*4+r
    const int col0 = n0 + wc * 64 + (lane & 15);
    const int row0 = m0 + wr * 64 + (lane >> 4) * 4;
    #pragma unroll
    for (int i = 0; i < 4; ++i)
        #pragma unroll
        for (int j = 0; j < 4; ++j) {
            const int col = col0 + j * 16;
            #pragma unroll
            for (int r = 0; r < 4; ++r) {
                float v = acc[i][j][r];
                if (SIGMOID) v = 1.f / (1.f + __expf(-v));
                const size_t o = (size_t)(row0 + i * 16 + r) * Cdim + col;
                if (OUT_BF16) ((u16*)O)[o] = f2bf(v);
                else          ((float*)O)[o] = v;
            }
        }
}

// ---------- WKV as constant-coefficient linear recurrence ----------
// pp_t = pp_{t-1} + max(td,0)  =>  all exp factors are per-channel constants:
//   aa_t = lam*aa_{t-1} + mu*v_t,  bb_t = lam*bb_{t-1} + mu
//   lam = exp(-max(td,0)), mu = exp(min(td,0))
//   wkv_t = (e1*aa_{t-1} + e2*v_t) / (e1*bb_{t-1} + e2 + 1e-6)
//   e1 = exp(-max(tf,0)), e2 = exp(min(tf,0))
// Chunk-parallel over T: pass1 computes per-chunk partial Sa; pass2 replays.

__global__ __launch_bounds__(256)
void wkv_pass1(const u16* __restrict__ Vb, const float* __restrict__ td,
               float* __restrict__ Sa)
{
    const int t = blockIdx.x * 256 + threadIdx.x;     // 0..131071
    const int c     = t & (Cdim - 1);
    const int chunk = (t >> 10) & (NCH - 1);
    const int b     = t >> 14;

    const float tdc = td[c];
    const float lam = __expf(-fmaxf(tdc, 0.f));
    const float mu  = __expf(fminf(tdc, 0.f));

    size_t idx = ((size_t)(b * Tn + chunk * CLEN)) * Cdim + c;
    float s = 0.f;
    for (int i = 0; i < CLEN; ++i, idx += Cdim)
        s = lam * s + mu * bf2f(Vb[idx]);
    Sa[t] = s;                                        // layout [b][chunk][c]
}

__global__ __launch_bounds__(256)
void wkv_pass2(const u16* __restrict__ Vb, const u16* __restrict__ Rb,
               const float* __restrict__ td, const float* __restrict__ tf,
               const float* __restrict__ Sa, u16* __restrict__ Y)
{
    const int t = blockIdx.x * 256 + threadIdx.x;
    const int c     = t & (Cdim - 1);
    const int chunk = (t >> 10) & (NCH - 1);
    const int b     = t >> 14;

    const float tdc = td[c], tfc = tf[c];
    const float lam  = __expf(-fmaxf(tdc, 0.f));
    const float mu   = __expf(fminf(tdc, 0.f));
    const float e1   = __expf(-fmaxf(tfc, 0.f));
    const float e2   = __expf(fminf(tfc, 0.f));
    const float lamL = __expf(-(float)CLEN * fmaxf(tdc, 0.f));
    const float Sb   = (fabsf(1.f - lam) < 1e-9f) ? mu * (float)CLEN
                                                  : mu * (1.f - lamL) / (1.f - lam);

    float aa = 0.f, bb = 0.f;
    for (int j = 0; j < chunk; ++j) {               // chunk is block-uniform
        aa = lamL * aa + Sa[(size_t)b * (NCH * Cdim) + j * Cdim + c];
        bb = lamL * bb + Sb;
    }

    size_t idx = ((size_t)(b * Tn + chunk * CLEN)) * Cdim + c;
    for (int i = 0; i < CLEN; ++i, idx += Cdim) {
        const float v = bf2f(Vb[idx]);
        const float r = bf2f(Rb[idx]);
        const float wkv = (e1 * aa + e2 * v) / (e1 * bb + e2 + 1e-6f);
        Y[idx] = f2bf(r * wkv);
        aa = lam * aa + mu * v;
        bb = lam * bb + mu;
    }
}

extern "C" void kernel_launch(void* const* d_in, const int* in_sizes, int n_in,
                              void* d_out, int out_size, void* d_ws, size_t ws_size,
                              hipStream_t stream)
{
    // inputs: x, time_decay, time_first, key_w(dead), value_w, recep_w, out_w
    const float* x       = (const float*)d_in[0];
    const float* td      = (const float*)d_in[1];
    const float* tf      = (const float*)d_in[2];
    const float* value_w = (const float*)d_in[4];
    const float* recep_w = (const float*)d_in[5];
    const float* out_w   = (const float*)d_in[6];
    float* out = (float*)d_out;

    char* ws = (char*)d_ws;
    const size_t MB = 1024 * 1024;
    u16*   Xb = (u16*)(ws);               // 32 MB [16384,1024] bf16 (Yb aliases after gemm2)
    u16*   Vb = (u16*)(ws + 32 * MB);     // 32 MB
    u16*   Rb = (u16*)(ws + 64 * MB);     // 32 MB
    u16*   Wv = (u16*)(ws + 96 * MB);     //  2 MB
    u16*   Wr = (u16*)(ws + 98 * MB);     //  2 MB
    u16*   Wo = (u16*)(ws + 100 * MB);    //  2 MB
    float* Sa = (float*)(ws + 102 * MB);  //  0.5 MB [8][16][1024]
    u16*   Yb = Xb;                       // alias: Xb dead after gemm2

    const int nX4 = (Mrows * Cdim) / 4;   // 4194304
    const int nW4 = (Cdim * Cdim) / 4;    // 262144
    cast_f32_bf16<<<nX4 / 256, 256, 0, stream>>>(x,       Xb, nX4);
    cast_f32_bf16<<<nW4 / 256, 256, 0, stream>>>(value_w, Wv, nW4);
    cast_f32_bf16<<<nW4 / 256, 256, 0, stream>>>(recep_w, Wr, nW4);
    cast_f32_bf16<<<nW4 / 256, 256, 0, stream>>>(out_w,   Wo, nW4);

    dim3 ggrid(Cdim / 128, Mrows / 128);  // (8, 128)
    gemm_mfma<false, true><<<ggrid, 256, 0, stream>>>(Xb, Wv, Vb);
    gemm_mfma<true,  true><<<ggrid, 256, 0, stream>>>(Xb, Wr, Rb);

    const int nScan = Bn * NCH * Cdim;    // 131072 threads
    wkv_pass1<<<nScan / 256, 256, 0, stream>>>(Vb, td, Sa);
    wkv_pass2<<<nScan / 256, 256, 0, stream>>>(Vb, Rb, td, tf, Sa, Yb);

    gemm_mfma<false, false><<<ggrid, 256, 0, stream>>>(Yb, Wo, out);
}

// Round 3
// 304.584 us; speedup vs baseline: 6.0433x; 1.1516x over previous
//
#include <hip/hip_runtime.h>

using u16 = unsigned short;
using u32 = unsigned int;

// Problem constants: B=8, T=2048, C=1024
constexpr int Cdim  = 1024;
constexpr int Bn    = 8;
constexpr int Tn    = 2048;
constexpr int Mrows = Bn * Tn;          // 16384 rows in all GEMMs
constexpr int NCH   = 16;               // wkv chunks per chain
constexpr int CLEN  = Tn / NCH;         // 128 steps per chunk

// ---------- bf16 helpers (bit-level, RNE) ----------
__device__ inline u16 f2bf(float x) {
    u32 u = __float_as_uint(x);
    u += 0x7fffu + ((u >> 16) & 1u);
    return (u16)(u >> 16);
}
__device__ inline float bf2f(u16 x) {
    return __uint_as_float(((u32)x) << 16);
}

// ---------- fp32 -> bf16 cast: X (large) ----------
__global__ __launch_bounds__(256)
void cast_f32_bf16(const float* __restrict__ in, u16* __restrict__ out, int n4) {
    int i = blockIdx.x * 256 + threadIdx.x;
    if (i < n4) {
        float4 v = ((const float4*)in)[i];
        ushort4 o;
        o.x = f2bf(v.x); o.y = f2bf(v.y); o.z = f2bf(v.z); o.w = f2bf(v.w);
        ((ushort4*)out)[i] = o;
    }
}

// ---------- fp32 -> bf16 cast: 3 weight matrices in one dispatch ----------
__global__ __launch_bounds__(256)
void cast_weights(const float* __restrict__ w0, const float* __restrict__ w1,
                  const float* __restrict__ w2,
                  u16* __restrict__ o0, u16* __restrict__ o1, u16* __restrict__ o2) {
    const int i = blockIdx.x * 256 + threadIdx.x;   // 0..262143
    const float* in  = (blockIdx.y == 0) ? w0 : (blockIdx.y == 1) ? w1 : w2;
    u16*         out = (blockIdx.y == 0) ? o0 : (blockIdx.y == 1) ? o1 : o2;
    float4 v = ((const float4*)in)[i];
    ushort4 o;
    o.x = f2bf(v.x); o.y = f2bf(v.y); o.z = f2bf(v.z); o.w = f2bf(v.w);
    ((ushort4*)out)[i] = o;
}

// ---------- MFMA bf16 NT-GEMM common bits ----------
typedef __bf16 bf16x8 __attribute__((ext_vector_type(8)));
typedef float  f32x4  __attribute__((ext_vector_type(4)));

__device__ inline void load_lds16(const void* g, void* l) {
    __builtin_amdgcn_global_load_lds(
        (const __attribute__((address_space(1))) void*)g,
        (__attribute__((address_space(3))) void*)l, 16, 0, 0);
}

// XCD-aware swizzle: linear block L -> (mt, nt) s.t. XCD (L&7) owns
// m-tiles [16k,16k+16) with the 8 n-tiles of one m-tile consecutive in time
// (A-tile stays hot in that XCD's private L2). Perf heuristic only.
__device__ inline void swizzle_tiles(int& mt, int& nt) {
    const int L   = blockIdx.y * gridDim.x + blockIdx.x;  // 0..1023
    const int xcd = L & 7;
    const int s   = L >> 3;          // 0..127
    mt = xcd * 16 + (s >> 3);        // 0..127
    nt = s & 7;                      // 0..7
}

// ---------- Dual-output GEMM: V = A@Wv^T (plain), R = sigmoid(A@Wr^T) ----------
__global__ __launch_bounds__(256, 2)
void gemm_dual(const u16* __restrict__ A, const u16* __restrict__ Wv,
               const u16* __restrict__ Wr, u16* __restrict__ Vb, u16* __restrict__ Rb)
{
    __shared__ alignas(16) u16 As[128 * 32];
    __shared__ alignas(16) u16 Bv[128 * 32];
    __shared__ alignas(16) u16 Br[128 * 32];

    const int tid  = threadIdx.x;
    const int wave = tid >> 6;
    const int lane = tid & 63;

    int mt, nt;
    swizzle_tiles(mt, nt);
    const int m0 = mt * 128;
    const int n0 = nt * 128;

    const int wr = wave >> 1;
    const int wc = wave & 1;

    const int srow = (lane >> 2);
    const int scol = (lane & 3) * 8;

    f32x4 accV[4][4] = {};
    f32x4 accR[4][4] = {};

    for (int kt = 0; kt < Cdim; kt += 32) {
        #pragma unroll
        for (int p = 0; p < 2; ++p) {
            const int row = wave * 32 + p * 16 + srow;
            const int lo  = wave * 2048 + p * 1024;
            load_lds16(A  + (size_t)(m0 + row) * Cdim + kt + scol, (char*)As + lo);
            load_lds16(Wv + (size_t)(n0 + row) * Cdim + kt + scol, (char*)Bv + lo);
            load_lds16(Wr + (size_t)(n0 + row) * Cdim + kt + scol, (char*)Br + lo);
        }
        __syncthreads();

        bf16x8 af[4], bv[4], br[4];
        #pragma unroll
        for (int i = 0; i < 4; ++i) {
            const int ar = (wr * 64 + i * 16 + (lane & 15)) * 32 + (lane >> 4) * 8;
            const int bc = (wc * 64 + i * 16 + (lane & 15)) * 32 + (lane >> 4) * 8;
            af[i] = *(const bf16x8*)&As[ar];
            bv[i] = *(const bf16x8*)&Bv[bc];
            br[i] = *(const bf16x8*)&Br[bc];
        }
        #pragma unroll
        for (int i = 0; i < 4; ++i)
            #pragma unroll
            for (int j = 0; j < 4; ++j) {
                accV[i][j] = __builtin_amdgcn_mfma_f32_16x16x32_bf16(af[i], bv[j], accV[i][j], 0, 0, 0);
                accR[i][j] = __builtin_amdgcn_mfma_f32_16x16x32_bf16(af[i], br[j], accR[i][j], 0, 0, 0);
            }
        __syncthreads();
    }

    const int col0 = n0 + wc * 64 + (lane & 15);
    const int row0 = m0 + wr * 64 + (lane >> 4) * 4;
    #pragma unroll
    for (int i = 0; i < 4; ++i)
        #pragma unroll
        for (int j = 0; j < 4; ++j) {
            const int col = col0 + j * 16;
            #pragma unroll
            for (int r = 0; r < 4; ++r) {
                const size_t o = (size_t)(row0 + i * 16 + r) * Cdim + col;
                Vb[o] = f2bf(accV[i][j][r]);
                const float rv = accR[i][j][r];
                Rb[o] = f2bf(1.f / (1.f + __expf(-rv)));
            }
        }
}

// ---------- Single GEMM: out = Y @ Wo^T (fp32 out) ----------
__global__ __launch_bounds__(256)
void gemm_single(const u16* __restrict__ A, const u16* __restrict__ W, float* __restrict__ O)
{
    __shared__ alignas(16) u16 As[128 * 32];
    __shared__ alignas(16) u16 Bs[128 * 32];

    const int tid  = threadIdx.x;
    const int wave = tid >> 6;
    const int lane = tid & 63;

    int mt, nt;
    swizzle_tiles(mt, nt);
    const int m0 = mt * 128;
    const int n0 = nt * 128;

    const int wr = wave >> 1;
    const int wc = wave & 1;

    const int srow = (lane >> 2);
    const int scol = (lane & 3) * 8;

    f32x4 acc[4][4] = {};

    for (int kt = 0; kt < Cdim; kt += 32) {
        #pragma unroll
        for (int p = 0; p < 2; ++p) {
            const int row = wave * 32 + p * 16 + srow;
            const int lo  = wave * 2048 + p * 1024;
            load_lds16(A + (size_t)(m0 + row) * Cdim + kt + scol, (char*)As + lo);
            load_lds16(W + (size_t)(n0 + row) * Cdim + kt + scol, (char*)Bs + lo);
        }
        __syncthreads();

        bf16x8 af[4], bfr[4];
        #pragma unroll
        for (int i = 0; i < 4; ++i) {
            af[i]  = *(const bf16x8*)&As[(wr * 64 + i * 16 + (lane & 15)) * 32 + (lane >> 4) * 8];
            bfr[i] = *(const bf16x8*)&Bs[(wc * 64 + i * 16 + (lane & 15)) * 32 + (lane >> 4) * 8];
        }
        #pragma unroll
        for (int i = 0; i < 4; ++i)
            #pragma unroll
            for (int j = 0; j < 4; ++j)
                acc[i][j] = __builtin_amdgcn_mfma_f32_16x16x32_bf16(af[i], bfr[j], acc[i][j], 0, 0, 0);
        __syncthreads();
    }

    const int col0 = n0 + wc * 64 + (lane & 15);
    const int row0 = m0 + wr * 64 + (lane >> 4) * 4;
    #pragma unroll
    for (int i = 0; i < 4; ++i)
        #pragma unroll
        for (int j = 0; j < 4; ++j) {
            const int col = col0 + j * 16;
            #pragma unroll
            for (int r = 0; r < 4; ++r)
                O[(size_t)(row0 + i * 16 + r) * Cdim + col] = acc[i][j][r];
        }
}

// ---------- WKV: constant-coefficient linear recurrence, chunk-parallel ----------
__global__ __launch_bounds__(256)
void wkv_pass1(const u16* __restrict__ Vb, const float* __restrict__ td,
               float* __restrict__ Sa)
{
    const int t = blockIdx.x * 256 + threadIdx.x;     // 0..131071
    const int c     = t & (Cdim - 1);
    const int chunk = (t >> 10) & (NCH - 1);
    const int b     = t >> 14;

    const float tdc = td[c];
    const float lam = __expf(-fmaxf(tdc, 0.f));
    const float mu  = __expf(fminf(tdc, 0.f));

    size_t idx = ((size_t)(b * Tn + chunk * CLEN)) * Cdim + c;
    float s = 0.f;
    for (int i = 0; i < CLEN; ++i, idx += Cdim)
        s = lam * s + mu * bf2f(Vb[idx]);
    Sa[t] = s;
}

__global__ __launch_bounds__(256)
void wkv_pass2(const u16* __restrict__ Vb, const u16* __restrict__ Rb,
               const float* __restrict__ td, const float* __restrict__ tf,
               const float* __restrict__ Sa, u16* __restrict__ Y)
{
    const int t = blockIdx.x * 256 + threadIdx.x;
    const int c     = t & (Cdim - 1);
    const int chunk = (t >> 10) & (NCH - 1);
    const int b     = t >> 14;

    const float tdc = td[c], tfc = tf[c];
    const float lam  = __expf(-fmaxf(tdc, 0.f));
    const float mu   = __expf(fminf(tdc, 0.f));
    const float e1   = __expf(-fmaxf(tfc, 0.f));
    const float e2   = __expf(fminf(tfc, 0.f));
    const float lamL = __expf(-(float)CLEN * fmaxf(tdc, 0.f));
    const float Sb   = (fabsf(1.f - lam) < 1e-9f) ? mu * (float)CLEN
                                                  : mu * (1.f - lamL) / (1.f - lam);

    float aa = 0.f, bb = 0.f;
    for (int j = 0; j < chunk; ++j) {
        aa = lamL * aa + Sa[(size_t)b * (NCH * Cdim) + j * Cdim + c];
        bb = lamL * bb + Sb;
    }

    size_t idx = ((size_t)(b * Tn + chunk * CLEN)) * Cdim + c;
    for (int i = 0; i < CLEN; ++i, idx += Cdim) {
        const float v = bf2f(Vb[idx]);
        const float r = bf2f(Rb[idx]);
        const float wkv = (e1 * aa + e2 * v) / (e1 * bb + e2 + 1e-6f);
        Y[idx] = f2bf(r * wkv);
        aa = lam * aa + mu * v;
        bb = lam * bb + mu;
    }
}

extern "C" void kernel_launch(void* const* d_in, const int* in_sizes, int n_in,
                              void* d_out, int out_size, void* d_ws, size_t ws_size,
                              hipStream_t stream)
{
    // inputs: x, time_decay, time_first, key_w(dead), value_w, recep_w, out_w
    const float* x       = (const float*)d_in[0];
    const float* td      = (const float*)d_in[1];
    const float* tf      = (const float*)d_in[2];
    const float* value_w = (const float*)d_in[4];
    const float* recep_w = (const float*)d_in[5];
    const float* out_w   = (const float*)d_in[6];
    float* out = (float*)d_out;

    char* ws = (char*)d_ws;
    const size_t MB = 1024 * 1024;
    u16*   Xb = (u16*)(ws);               // 32 MB; reused as Yb after dual GEMM+wkv
    u16*   Vb = (u16*)(ws + 32 * MB);     // 32 MB
    u16*   Rb = (u16*)(ws + 64 * MB);     // 32 MB
    u16*   Wv = (u16*)(ws + 96 * MB);     //  2 MB
    u16*   Wr = (u16*)(ws + 98 * MB);     //  2 MB
    u16*   Wo = (u16*)(ws + 100 * MB);    //  2 MB
    float* Sa = (float*)(ws + 102 * MB);  //  0.5 MB [8][16][1024]
    u16*   Yb = Xb;                       // alias: Xb dead after dual GEMM

    const int nX4 = (Mrows * Cdim) / 4;   // 4194304
    const int nW4 = (Cdim * Cdim) / 4;    // 262144
    cast_f32_bf16<<<nX4 / 256, 256, 0, stream>>>(x, Xb, nX4);
    cast_weights<<<dim3(nW4 / 256, 3), 256, 0, stream>>>(value_w, recep_w, out_w, Wv, Wr, Wo);

    dim3 ggrid(Cdim / 128, Mrows / 128);  // (8, 128) -> 1024 blocks
    gemm_dual<<<ggrid, 256, 0, stream>>>(Xb, Wv, Wr, Vb, Rb);

    const int nScan = Bn * NCH * Cdim;    // 131072 threads
    wkv_pass1<<<nScan / 256, 256, 0, stream>>>(Vb, td, Sa);
    wkv_pass2<<<nScan / 256, 256, 0, stream>>>(Vb, Rb, td, tf, Sa, Yb);

    gemm_single<<<ggrid, 256, 0, stream>>>(Yb, Wo, out);
}